// Round 4
// 1009.114 us; speedup vs baseline: 1.0009x; 1.0009x over previous
//
#include <hip/hip_runtime.h>
#include <hip/hip_bf16.h>
#include <math.h>

#define BB  32
#define TVV 3200
#define XB  819200   // 256*3200 floats per batch

typedef __attribute__((ext_vector_type(8))) short s8v;   // 8 x bf16
typedef __attribute__((ext_vector_type(4))) float f4v;   // MFMA acc
typedef unsigned short u16;
typedef unsigned int   u32;

__device__ __forceinline__ u16 f2bf(float f) {
  __hip_bfloat16 h = __float2bfloat16(f);
  union { __hip_bfloat16 h; u16 u; } cv; cv.h = h; return cv.u;
}
__device__ __forceinline__ float bf2f(u16 u) {
  return __uint_as_float(((u32)u) << 16);
}

// async global->LDS, 16B per lane; lds dest = wave-uniform base + lane*16
__device__ __forceinline__ void glds16(const u16* g, u16* l) {
  __builtin_amdgcn_global_load_lds((const __attribute__((address_space(1))) u32*)g,
                                   (__attribute__((address_space(3))) u32*)l, 16, 0, 0);
}

// ---------------- m97-style MFMA core: C(128x128) = A(M,K) x B(N,K)^T
// LDS tiles 128x32 bf16 (row = 64B = 4 x 16B slots). Slot is XOR-swizzled with
// ((row>>1)&3) on BOTH sides (rule #21):
//   - stage: lane l writes LDS (row=l>>2, slot=l&3) [linear, glds-required], so the
//     per-lane GLOBAL source is pre-swizzled: slot (l&3)^((l>>3)&3)
//   - read:  global (r,q) lives at LDS slot q^((r>>1)&3)
// Bank-quad of (row,slot) = (row&1, slot): each 8-lane b128 phase (l15 0..7, fixed q)
// hits 8 distinct quads -> conflict-free (was 4-way = 16 extra cyc/instr, measured).
template<int K>
__device__ __forceinline__ void gemm_core(const u16* __restrict__ A, const u16* __restrict__ B,
                                          int m0, int n0, u16* sA, u16* sB, f4v (&acc)[4][4]) {
  const int tid = threadIdx.x, lane = tid & 63, wave = tid >> 6;
  const int wr = wave >> 1, wc = wave & 1;
  const int q = lane >> 4, l15 = lane & 15;
  const int srow = lane >> 2;                         // 0..15
  const int sslot = (lane & 3) ^ ((lane >> 3) & 3);   // pre-swizzled source slot
  const u16* gA = A + (size_t)(m0 + wave * 32 + srow) * K + sslot * 8;
  const u16* gB = B + (size_t)(n0 + wave * 32 + srow) * K + sslot * 8;
  u16* lA = sA + wave * 1024;               // rows 32w..  (row*32 elems)
  u16* lB = sB + wave * 1024;
  const int sw = ((l15 >> 1) & 3) << 3;     // read-side swizzle (elems)
  for (int k0 = 0; k0 < K; k0 += 32) {
    glds16(gA + k0,                  lA);
    glds16(gA + k0 + (size_t)16 * K, lA + 512);
    glds16(gB + k0,                  lB);
    glds16(gB + k0 + (size_t)16 * K, lB + 512);
    __syncthreads();
    s8v af[4], bfr[4];
#pragma unroll
    for (int i = 0; i < 4; ++i) {
      af[i]  = *(const s8v*)(sA + (wr * 64 + i * 16 + l15) * 32 + ((q << 3) ^ sw));
      bfr[i] = *(const s8v*)(sB + (wc * 64 + i * 16 + l15) * 32 + ((q << 3) ^ sw));
    }
#pragma unroll
    for (int mi = 0; mi < 4; ++mi)
#pragma unroll
      for (int ni = 0; ni < 4; ++ni)
        acc[mi][ni] = __builtin_amdgcn_mfma_f32_16x16x32_bf16(af[mi], bfr[ni], acc[mi][ni], 0, 0, 0);
    __syncthreads();
  }
}

// ---------------- weight prep: src fp32 (K,N) -> dst bf16 (N,K)
__global__ __launch_bounds__(256)
void k_wprep(const float* __restrict__ src, u16* __restrict__ dst, int K, int N) {
  int idx = blockIdx.x * 256 + threadIdx.x;
  if (idx >= N * K) return;
  int n = idx / K, k = idx - n * K;
  dst[idx] = f2bf(src[(size_t)k * N + n]);
}

// ---------------- fused transpose + LN1: x (B,C,T,V) -> xtok fp32 (Mc,256) + xln bf16 (Mc,256)
// one block = 32 tokens x 256 channels
__global__ __launch_bounds__(256)
void k_lnx(const float* __restrict__ x, int b0, const float* __restrict__ w,
           const float* __restrict__ bias, float* __restrict__ xtok, u16* __restrict__ xln) {
  __shared__ float sx[32][264];        // [tok][ch], pad to 264
  __shared__ float srs_[32][33], srq_[32][33];
  __shared__ float smu[32], sst[32];
  int m0 = blockIdx.x * 32;
  int b = b0 + m0 / TVV, tv0 = m0 % TVV;
  int tid = threadIdx.x;
  int qd = tid & 7, c = tid >> 3;      // qd: float4-slot (token quad), c: 0..31
  const float* xb = x + (size_t)b * XB + tv0;
  float wreg = w[tid], breg = bias[tid];
  float s[4] = {0.f, 0.f, 0.f, 0.f}, ss[4] = {0.f, 0.f, 0.f, 0.f};
#pragma unroll
  for (int k = 0; k < 8; ++k) {
    int cc = k * 32 + c;
    float4 vv = *(const float4*)(xb + (size_t)cc * TVV + qd * 4);
    sx[qd * 4 + 0][cc] = vv.x; sx[qd * 4 + 1][cc] = vv.y;
    sx[qd * 4 + 2][cc] = vv.z; sx[qd * 4 + 3][cc] = vv.w;
    s[0] += vv.x; s[1] += vv.y; s[2] += vv.z; s[3] += vv.w;
    ss[0] += vv.x * vv.x; ss[1] += vv.y * vv.y; ss[2] += vv.z * vv.z; ss[3] += vv.w * vv.w;
  }
#pragma unroll
  for (int i = 0; i < 4; ++i) { srs_[qd * 4 + i][c] = s[i]; srq_[qd * 4 + i][c] = ss[i]; }
  __syncthreads();
  if (tid < 32) {
    float t1 = 0.f, t2 = 0.f;
#pragma unroll
    for (int j = 0; j < 32; ++j) { t1 += srs_[tid][j]; t2 += srq_[tid][j]; }
    float mu = t1 * (1.f / 256.f);
    smu[tid] = mu;
    sst[tid] = rsqrtf(t2 * (1.f / 256.f) - mu * mu + 1e-5f);
  }
  __syncthreads();
  for (int tok = 0; tok < 32; ++tok) {
    float val = sx[tok][tid];
    float mu = smu[tok], rs = sst[tok];
    size_t m = (size_t)(m0 + tok) * 256 + tid;
    xtok[m] = val;
    xln[m]  = f2bf((val - mu) * rs * wreg + breg);
  }
}

// ---------------- LayerNorm (over 256) fp32 token-major src -> bf16 dst
__global__ __launch_bounds__(256)
void k_ln(const float* __restrict__ src, const float* __restrict__ w, const float* __restrict__ b,
          u16* __restrict__ dst) {
  int tid = threadIdx.x;
  int tk = tid >> 2, p = tid & 3;
  size_t m = (size_t)blockIdx.x * 64 + tk;
  const float4* row = (const float4*)(src + m * 256 + p * 64);
  float4 r[16];
  float s = 0.f, ss = 0.f;
#pragma unroll
  for (int j = 0; j < 16; ++j) {
    r[j] = row[j];
    s  += r[j].x + r[j].y + r[j].z + r[j].w;
    ss += r[j].x*r[j].x + r[j].y*r[j].y + r[j].z*r[j].z + r[j].w*r[j].w;
  }
  __shared__ float sb1[256], sb2[256];
  sb1[tid] = s; sb2[tid] = ss;
  __syncthreads();
  int base = tk << 2;
  s  = sb1[base] + sb1[base+1] + sb1[base+2] + sb1[base+3];
  ss = sb2[base] + sb2[base+1] + sb2[base+2] + sb2[base+3];
  float mu = s * (1.f / 256.f);
  float rstd = rsqrtf(ss * (1.f / 256.f) - mu * mu + 1e-5f);
  ushort4* drow = (ushort4*)(dst + m * 256 + p * 64);
#pragma unroll
  for (int j = 0; j < 16; ++j) {
    int c = p * 64 + j * 4;
    ushort4 o;
    o.x = f2bf((r[j].x - mu) * rstd * w[c]     + b[c]);
    o.y = f2bf((r[j].y - mu) * rstd * w[c + 1] + b[c + 1]);
    o.z = f2bf((r[j].z - mu) * rstd * w[c + 2] + b[c + 2]);
    o.w = f2bf((r[j].w - mu) * rstd * w[c + 3] + b[c + 3]);
    drow[j] = o;
  }
}

// ---------------- map GEMM: xln(Mc,256) x wmapT(512,256) + bias -> f bf16 (Mc,512)
__global__ __launch_bounds__(256)
void k_gemm_map(const u16* __restrict__ xln, const u16* __restrict__ wT,
                const float* __restrict__ bias, u16* __restrict__ f) {
  __shared__ __align__(16) u16 sm[8192];
  int m0 = blockIdx.x * 128, n0 = blockIdx.y * 128;
  f4v acc[4][4];
#pragma unroll
  for (int i = 0; i < 4; ++i)
#pragma unroll
    for (int j = 0; j < 4; ++j) acc[i][j] = (f4v){0.f, 0.f, 0.f, 0.f};
  gemm_core<256>(xln, wT, m0, n0, sm, sm + 4096, acc);
  const int tid = threadIdx.x, lane = tid & 63, wave = tid >> 6;
  const int wr = wave >> 1, wc = wave & 1, q = lane >> 4, l15 = lane & 15;
#pragma unroll
  for (int ni = 0; ni < 4; ++ni) {
    int n = n0 + wc * 64 + ni * 16 + l15;
    float bz = bias[n];
#pragma unroll
    for (int mi = 0; mi < 4; ++mi) {
      int m = m0 + wr * 64 + mi * 16 + q * 4;
#pragma unroll
      for (int rr = 0; rr < 4; ++rr)
        f[(size_t)(m + rr) * 512 + n] = f2bf(acc[mi][ni][rr] + bz);
    }
  }
}

// ---------------- proj GEMM: ycat(Mc,256) x wprojT(256,256) + bias + skip (in-place xtok)
__global__ __launch_bounds__(256)
void k_gemm_proj(const u16* __restrict__ ycat, const u16* __restrict__ wT,
                 const float* __restrict__ bias, float* __restrict__ out1) {
  __shared__ __align__(16) u16 sm[8192];
  int m0 = blockIdx.x * 128, n0 = blockIdx.y * 128;
  f4v acc[4][4];
#pragma unroll
  for (int i = 0; i < 4; ++i)
#pragma unroll
    for (int j = 0; j < 4; ++j) acc[i][j] = (f4v){0.f, 0.f, 0.f, 0.f};
  gemm_core<256>(ycat, wT, m0, n0, sm, sm + 4096, acc);
  const int tid = threadIdx.x, lane = tid & 63, wave = tid >> 6;
  const int wr = wave >> 1, wc = wave & 1, q = lane >> 4, l15 = lane & 15;
#pragma unroll
  for (int ni = 0; ni < 4; ++ni) {
    int n = n0 + wc * 64 + ni * 16 + l15;
    float bz = bias[n];
#pragma unroll
    for (int mi = 0; mi < 4; ++mi) {
      int m = m0 + wr * 64 + mi * 16 + q * 4;
#pragma unroll
      for (int rr = 0; rr < 4; ++rr) {
        size_t idx = (size_t)(m + rr) * 256 + n;
        out1[idx] = out1[idx] + acc[mi][ni][rr] + bz;
      }
    }
  }
}

// ---------------- mlp1 GEMM: xln2(Mc,256) x w1T(1024,256) + bias -> GELU -> hmid bf16 (Mc,1024)
__global__ __launch_bounds__(256)
void k_gemm_mlp1(const u16* __restrict__ xln2, const u16* __restrict__ wT,
                 const float* __restrict__ bias, u16* __restrict__ hmid) {
  __shared__ __align__(16) u16 sm[8192];
  int m0 = blockIdx.x * 128, n0 = blockIdx.y * 128;
  f4v acc[4][4];
#pragma unroll
  for (int i = 0; i < 4; ++i)
#pragma unroll
    for (int j = 0; j < 4; ++j) acc[i][j] = (f4v){0.f, 0.f, 0.f, 0.f};
  gemm_core<256>(xln2, wT, m0, n0, sm, sm + 4096, acc);
  const int tid = threadIdx.x, lane = tid & 63, wave = tid >> 6;
  const int wr = wave >> 1, wc = wave & 1, q = lane >> 4, l15 = lane & 15;
#pragma unroll
  for (int ni = 0; ni < 4; ++ni) {
    int n = n0 + wc * 64 + ni * 16 + l15;
    float bz = bias[n];
#pragma unroll
    for (int mi = 0; mi < 4; ++mi) {
      int m = m0 + wr * 64 + mi * 16 + q * 4;
#pragma unroll
      for (int rr = 0; rr < 4; ++rr) {
        float h = acc[mi][ni][rr] + bz;
        float g = 0.5f * h * (1.f + erff(h * 0.70710678118654752f));
        hmid[(size_t)(m + rr) * 1024 + n] = f2bf(g);
      }
    }
  }
}

// ---------------- mlp2 GEMM: hmid(Mc,1024) x w2T(256,1024) + bias + out1 -> d_out (B,C,T,V)
__global__ __launch_bounds__(256)
void k_gemm_mlp2(const u16* __restrict__ hmid, const u16* __restrict__ wT,
                 const float* __restrict__ bias, const float* __restrict__ out1,
                 float* __restrict__ out, int b0) {
  __shared__ __align__(16) u16 sm[10240];   // 20480 B: 16 KB tiles + transpose scratch
  int m0 = blockIdx.x * 128, n0 = blockIdx.y * 128;
  f4v acc[4][4];
#pragma unroll
  for (int i = 0; i < 4; ++i)
#pragma unroll
    for (int j = 0; j < 4; ++j) acc[i][j] = (f4v){0.f, 0.f, 0.f, 0.f};
  gemm_core<1024>(hmid, wT, m0, n0, sm, sm + 4096, acc);
  const int tid = threadIdx.x, lane = tid & 63, wave = tid >> 6;
  const int wr = wave >> 1, wc = wave & 1, q = lane >> 4, l15 = lane & 15;
  float* twv = (float*)sm + wave * 16 * 65;   // 4 waves * 1040 floats = 16640 B
  int mbase = m0 + wr * 64;
  int bglob = b0 + mbase / TVV;
  int tvb = mbase % TVV;
  for (int ni = 0; ni < 4; ++ni) {
    int n = n0 + wc * 64 + ni * 16 + l15;
    float bz = bias[n];
#pragma unroll
    for (int mi = 0; mi < 4; ++mi) {
      int ml = mi * 16 + q * 4;
#pragma unroll
      for (int rr = 0; rr < 4; ++rr) {
        int m = mbase + ml + rr;
        twv[l15 * 65 + ml + rr] = acc[mi][ni][rr] + bz + out1[(size_t)m * 256 + n];
      }
    }
    __syncthreads();
#pragma unroll
    for (int np = 0; np < 16; ++np) {
      int n2 = n0 + wc * 64 + ni * 16 + np;
      out[((size_t)bglob * 256 + n2) * TVV + tvb + lane] = twv[np * 65 + lane];
    }
    __syncthreads();
  }
}

// ---------------- grouped graph conv over V: f ch 0..63 -> ycat ch 0..63
__global__ __launch_bounds__(256)
void k_gconv(const u16* __restrict__ f, const float* __restrict__ gw,
             u16* __restrict__ ycat) {
  __shared__ float sf[50][64];
  int bc = blockIdx.x >> 6, t = blockIdx.x & 63;
  int tid = threadIdx.x;
  size_t tok0 = (size_t)bc * TVV + t * 50;
  for (int idx = tid; idx < 3200; idx += 256) {
    int u = idx >> 6, oc = idx & 63;
    sf[u][oc] = bf2f(f[(tok0 + u) * 512 + oc]);
  }
  __syncthreads();
  for (int idx = tid; idx < 3200; idx += 256) {
    int v = idx >> 6, oc = idx & 63;
    const float* gr = gw + ((size_t)(oc >> 3) * 50 + v) * 50;
    float s = 0.f;
#pragma unroll 10
    for (int u = 0; u < 50; ++u) s += sf[u][oc] * gr[u];
    ycat[(tok0 + v) * 256 + oc] = f2bf(s);
  }
}

// ---------------- grouped temporal conv k=7 pad3: f ch 64..127 -> ycat ch 64..127
__global__ __launch_bounds__(256)
void k_tconv(const u16* __restrict__ f, const float* __restrict__ tw,
             const float* __restrict__ tb, u16* __restrict__ ycat) {
  __shared__ float sw[64 * 57];
  int bc = blockIdx.x >> 6, t = blockIdx.x & 63;
  int tid = threadIdx.x;
  for (int idx = tid; idx < 64 * 56; idx += 256) {
    int oc = idx / 56, k = idx - oc * 56;
    sw[oc * 57 + k] = tw[idx];
  }
  __syncthreads();
  size_t base = (size_t)bc * TVV;
  for (int idx = tid; idx < 3200; idx += 256) {
    int v = idx >> 6, oc = idx & 63;
    int g = oc >> 3;
    float s = tb[oc];
#pragma unroll
    for (int kt = 0; kt < 7; ++kt) {
      int ts = t + kt - 3;
      if (ts < 0 || ts >= 64) continue;
      s8v fv = *(const s8v*)(f + (base + ts * 50 + v) * 512 + 64 + g * 8);
      const float* wr_ = sw + oc * 57 + kt;
#pragma unroll
      for (int ic = 0; ic < 8; ++ic) s += bf2f((u16)fv[ic]) * wr_[ic * 7];
    }
    ycat[(base + t * 50 + v) * 256 + 64 + oc] = f2bf(s);
  }
}

// ---------------- windowed hyperbolic linear attention -> ycat ch 128..255
__global__ __launch_bounds__(256)
void k_attn(const u16* __restrict__ f, u16* __restrict__ ycat) {
  int mode = blockIdx.z, bc = blockIdx.y;
  int wt = blockIdx.x / 5, wv = blockIdx.x % 5;
  __shared__ float parts[80][97];
  __shared__ float kvb[256];
  __shared__ float obuf[80][33];
  __shared__ float scl[80];
  __shared__ float pp[80][4];
  int tid = threadIdx.x;
  size_t base = (size_t)bc * TVV;
  int ch0 = 128 + mode * 96;
  for (int idx = tid; idx < 80 * 96; idx += 256) {
    int n = idx / 96, ch = idx - n * 96;
    int lt = n / 10, lv = n - lt * 10;
    int t = (mode < 2) ? (wt * 8 + lt) : (lt * 8 + wt);
    int v = ((mode & 1) == 0) ? (wv * 10 + lv) : (lv * 5 + wv);
    parts[n][ch] = bf2f(f[(base + t * 50 + v) * 512 + ch0 + ch]);
  }
  __syncthreads();
  // euc->poincare norm: parallel partial sums (80 rows x 4 partials of 24 ch)
  for (int idx = tid; idx < 320; idx += 256) {
    int n = idx >> 2, p = idx & 3;
    const float* pr = &parts[n][p * 24];
    float s = 0.f;
#pragma unroll
    for (int ch = 0; ch < 24; ++ch) { float val = pr[ch]; s += val * val; }
    pp[n][p] = s;
  }
  __syncthreads();
  if (tid < 80) {
    float s = pp[tid][0] + pp[tid][1] + pp[tid][2] + pp[tid][3];
    float nrm = fmaxf(sqrtf(s), 1e-10f);
    scl[tid] = tanhf(nrm) / nrm;
  }
  __syncthreads();
  for (int idx = tid; idx < 80 * 96; idx += 256) {
    int n = idx / 96, ch = idx - n * 96;
    parts[n][ch] *= scl[n];
  }
  __syncthreads();
  {
    int h = tid >> 6, dd = (tid >> 3) & 7, e = tid & 7;
    float s = 0.f;
    for (int n = 0; n < 80; ++n)
      s += parts[n][32 + h * 8 + dd] * parts[n][64 + h * 8 + e];
    kvb[tid] = s;
  }
  __syncthreads();
  if (tid < 32) {
    int h = tid >> 3, dd = tid & 7;
    float* r = &kvb[h * 64 + dd * 8];
    float mx = r[0];
    for (int e = 1; e < 8; ++e) mx = fmaxf(mx, r[e]);
    float ex[8]; float sm2 = 0.f;
    for (int e = 0; e < 8; ++e) { ex[e] = expf(r[e] - mx); sm2 += ex[e]; }
    float inv = 1.f / sm2;
    for (int e = 0; e < 8; ++e) r[e] = ex[e] * inv;
  }
  __syncthreads();
  for (int idx = tid; idx < 80 * 32; idx += 256) {
    int n = idx >> 5, cc = idx & 31;
    int h = cc >> 3, m_ = cc & 7;
    float s = 0.f;
#pragma unroll
    for (int i = 0; i < 8; ++i)
      s += parts[n][h * 8 + i] * kvb[h * 64 + m_ * 8 + i];
    obuf[n][cc] = s * 0.5f;
  }
  __syncthreads();
  // poincare->euc norm: parallel partial sums (80 rows x 2 partials of 16 ch)
  for (int idx = tid; idx < 160; idx += 256) {
    int n = idx >> 1, p = idx & 1;
    const float* orow = &obuf[n][p * 16];
    float s = 0.f;
#pragma unroll
    for (int cc = 0; cc < 16; ++cc) { float val = orow[cc]; s += val * val; }
    pp[n][p] = s;
  }
  __syncthreads();
  if (tid < 80) {
    float nn = sqrtf(pp[tid][0] + pp[tid][1]);
    nn = fminf(fmaxf(nn, 1e-10f), 1.f - 1e-5f);
    scl[tid] = -atanhf(nn) / nn;
  }
  __syncthreads();
  for (int idx = tid; idx < 80 * 32; idx += 256) {
    int n = idx >> 5, cc = idx & 31;
    int lt = n / 10, lv = n - lt * 10;
    int t = (mode < 2) ? (wt * 8 + lt) : (lt * 8 + wt);
    int v = ((mode & 1) == 0) ? (wv * 10 + lv) : (lv * 5 + wv);
    ycat[(base + t * 50 + v) * 256 + 128 + mode * 32 + cc] = f2bf(obuf[n][cc] * scl[n]);
  }
}

extern "C" void kernel_launch(void* const* d_in, const int* in_sizes, int n_in,
                              void* d_out, int out_size, void* d_ws, size_t ws_size,
                              hipStream_t stream) {
  const float* x       = (const float*)d_in[0];
  const float* n1w     = (const float*)d_in[1];
  const float* n1b     = (const float*)d_in[2];
  const float* map_w   = (const float*)d_in[3];
  const float* map_b   = (const float*)d_in[4];
  const float* gconv   = (const float*)d_in[5];
  const float* tconv_w = (const float*)d_in[6];
  const float* tconv_b = (const float*)d_in[7];
  const float* proj_w  = (const float*)d_in[8];
  const float* proj_b  = (const float*)d_in[9];
  const float* n2w     = (const float*)d_in[10];
  const float* n2b     = (const float*)d_in[11];
  const float* w1      = (const float*)d_in[12];
  const float* b1      = (const float*)d_in[13];
  const float* w2      = (const float*)d_in[14];
  const float* b2      = (const float*)d_in[15];
  float* out = (float*)d_out;

  // per-token ws: xtok/out1 fp32 (1024 B) | region2 2048 B: f bf16 (Mc,512) overlaid
  // with hmid bf16 (Mc,1024) | xln bf16 (512 B) | ycat bf16 (512 B) = 4096 B/token
  const size_t WB = (size_t)(512 * 256 + 256 * 256 + 1024 * 256 + 256 * 1024) * 2;
  int CH = 32;
  while (CH > 1 && (size_t)CH * TVV * 4096 + WB > ws_size) CH >>= 1;
  if ((size_t)CH * TVV * 4096 + WB > ws_size) return;
  const int Mc = CH * TVV;
  const int nch = BB / CH;

  char* ws = (char*)d_ws;
  float* xtok   = (float*)ws;                                // (Mc,256) fp32; becomes out1
  u16* f        = (u16*)(ws + (size_t)Mc * 1024);            // (Mc,512) bf16
  u16* hmid     = f;                                         // (Mc,1024) bf16 overlay
  u16* xln      = (u16*)(ws + (size_t)Mc * 3072);            // (Mc,256) bf16
  u16* ycat     = (u16*)(ws + (size_t)Mc * 3584);            // (Mc,256) bf16
  u16* wmapT    = (u16*)(ws + (size_t)Mc * 4096);            // (512,256)
  u16* wprojT   = wmapT + 512 * 256;                         // (256,256)
  u16* w1T      = wprojT + 256 * 256;                        // (1024,256)
  u16* w2T      = w1T + 1024 * 256;                          // (256,1024)

  k_wprep<<<dim3(512), 256, 0, stream>>>(map_w, wmapT, 256, 512);
  k_wprep<<<dim3(256), 256, 0, stream>>>(proj_w, wprojT, 256, 256);
  k_wprep<<<dim3(1024), 256, 0, stream>>>(w1, w1T, 256, 1024);
  k_wprep<<<dim3(1024), 256, 0, stream>>>(w2, w2T, 1024, 256);

  for (int c = 0; c < nch; ++c) {
    int b0 = c * CH;
    k_lnx<<<dim3(Mc / 32), 256, 0, stream>>>(x, b0, n1w, n1b, xtok, xln);
    k_gemm_map<<<dim3(Mc / 128, 4), 256, 0, stream>>>(xln, wmapT, map_b, f);
    k_gconv<<<dim3(CH * 64), 256, 0, stream>>>(f, gconv, ycat);
    k_tconv<<<dim3(CH * 64), 256, 0, stream>>>(f, tconv_w, tconv_b, ycat);
    k_attn<<<dim3(40, CH, 4), 256, 0, stream>>>(f, ycat);
    k_gemm_proj<<<dim3(Mc / 128, 2), 256, 0, stream>>>(ycat, wprojT, proj_b, xtok);
    k_ln<<<dim3(Mc / 64), 256, 0, stream>>>(xtok, n2w, n2b, xln);
    k_gemm_mlp1<<<dim3(Mc / 128, 8), 256, 0, stream>>>(xln, w1T, b1, hmid);
    k_gemm_mlp2<<<dim3(Mc / 128, 2), 256, 0, stream>>>(hmid, w2T, b2, xtok, out, b0);
  }
}

// Round 5
// 989.010 us; speedup vs baseline: 1.0213x; 1.0203x over previous
//
#include <hip/hip_runtime.h>
#include <hip/hip_bf16.h>
#include <math.h>

#define BB  32
#define TVV 3200
#define XB  819200   // 256*3200 floats per batch

typedef __attribute__((ext_vector_type(8))) short s8v;   // 8 x bf16
typedef __attribute__((ext_vector_type(4))) float f4v;   // MFMA acc
typedef unsigned short u16;
typedef unsigned int   u32;

__device__ __forceinline__ u16 f2bf(float f) {
  __hip_bfloat16 h = __float2bfloat16(f);
  union { __hip_bfloat16 h; u16 u; } cv; cv.h = h; return cv.u;
}
__device__ __forceinline__ float bf2f(u16 u) {
  return __uint_as_float(((u32)u) << 16);
}

// async global->LDS, 16B per lane; lds dest = wave-uniform base + lane*16
__device__ __forceinline__ void glds16(const u16* g, u16* l) {
  __builtin_amdgcn_global_load_lds((const __attribute__((address_space(1))) u32*)g,
                                   (__attribute__((address_space(3))) u32*)l, 16, 0, 0);
}

// ---------------- MFMA core, 2-phase double-buffered (T3-minimum recipe).
// C(128x128) = A(M,K) x B(N,K)^T.  LDS: two 16KB buffers (A 4096 + B 4096 elems each).
// LINEAR lane-order layout (row r at r*32 elems) — NO source/read swizzle: round-4
// A/B showed pre-swizzled per-lane global sources cost +30% on the glds path, far
// more than the 4 cyc/b128 bank conflict they remove.
// Schedule per k-step: issue next-tile glds -> ds_read+MFMA on cur -> barrier.
// The barrier's vmcnt(0) drain overlaps load latency with this step's compute.
template<int K>
__device__ __forceinline__ void gemm_core(const u16* __restrict__ A, const u16* __restrict__ B,
                                          int m0, int n0, u16* sm, f4v (&acc)[4][4]) {
  const int tid = threadIdx.x, lane = tid & 63, wave = tid >> 6;
  const int wr = wave >> 1, wc = wave & 1;
  const int q = lane >> 4, l15 = lane & 15;
  const int srow = lane >> 2;               // 0..15
  const int skq  = (lane & 3) << 3;         // 0,8,16,24 elems
  const u16* gA = A + (size_t)(m0 + wave * 32 + srow) * K + skq;
  const u16* gB = B + (size_t)(n0 + wave * 32 + srow) * K + skq;
  const int woff = wave * 1024;

  // prologue: stage tile 0 into buf 0
  glds16(gA,                  sm + woff);
  glds16(gA + (size_t)16 * K, sm + woff + 512);
  glds16(gB,                  sm + 4096 + woff);
  glds16(gB + (size_t)16 * K, sm + 4096 + woff + 512);
  __syncthreads();                          // vmcnt(0) drain -> buf0 ready

#pragma unroll 2
  for (int k0 = 0; k0 < K; k0 += 32) {
    const int cur = (k0 >> 5) & 1;
    u16* buf = sm + cur * 8192;
    if (k0 + 32 < K) {                      // issue next-tile loads BEFORE compute
      u16* nb = sm + (cur ^ 1) * 8192;
      glds16(gA + k0 + 32,                  nb + woff);
      glds16(gA + k0 + 32 + (size_t)16 * K, nb + woff + 512);
      glds16(gB + k0 + 32,                  nb + 4096 + woff);
      glds16(gB + k0 + 32 + (size_t)16 * K, nb + 4096 + woff + 512);
    }
    s8v af[4], bfr[4];
#pragma unroll
    for (int i = 0; i < 4; ++i) {
      af[i]  = *(const s8v*)(buf + (wr * 64 + i * 16 + l15) * 32 + q * 8);
      bfr[i] = *(const s8v*)(buf + 4096 + (wc * 64 + i * 16 + l15) * 32 + q * 8);
    }
#pragma unroll
    for (int mi = 0; mi < 4; ++mi)
#pragma unroll
      for (int ni = 0; ni < 4; ++ni)
        acc[mi][ni] = __builtin_amdgcn_mfma_f32_16x16x32_bf16(af[mi], bfr[ni], acc[mi][ni], 0, 0, 0);
    __syncthreads();   // drains vmcnt(0): next buf ready; all waves done reading cur
  }
}

// ---------------- weight prep: src fp32 (K,N) -> dst bf16 (N,K)
__global__ __launch_bounds__(256)
void k_wprep(const float* __restrict__ src, u16* __restrict__ dst, int K, int N) {
  int idx = blockIdx.x * 256 + threadIdx.x;
  if (idx >= N * K) return;
  int n = idx / K, k = idx - n * K;
  dst[idx] = f2bf(src[(size_t)k * N + n]);
}

// ---------------- fused transpose + LN1: x (B,C,T,V) -> xtok fp32 (Mc,256) + xln bf16 (Mc,256)
// one block = 32 tokens x 256 channels
__global__ __launch_bounds__(256)
void k_lnx(const float* __restrict__ x, int b0, const float* __restrict__ w,
           const float* __restrict__ bias, float* __restrict__ xtok, u16* __restrict__ xln) {
  __shared__ float sx[32][264];        // [tok][ch], pad to 264
  __shared__ float srs_[32][33], srq_[32][33];
  __shared__ float smu[32], sst[32];
  int m0 = blockIdx.x * 32;
  int b = b0 + m0 / TVV, tv0 = m0 % TVV;
  int tid = threadIdx.x;
  int qd = tid & 7, c = tid >> 3;      // qd: float4-slot (token quad), c: 0..31
  const float* xb = x + (size_t)b * XB + tv0;
  float wreg = w[tid], breg = bias[tid];
  float s[4] = {0.f, 0.f, 0.f, 0.f}, ss[4] = {0.f, 0.f, 0.f, 0.f};
#pragma unroll
  for (int k = 0; k < 8; ++k) {
    int cc = k * 32 + c;
    float4 vv = *(const float4*)(xb + (size_t)cc * TVV + qd * 4);
    sx[qd * 4 + 0][cc] = vv.x; sx[qd * 4 + 1][cc] = vv.y;
    sx[qd * 4 + 2][cc] = vv.z; sx[qd * 4 + 3][cc] = vv.w;
    s[0] += vv.x; s[1] += vv.y; s[2] += vv.z; s[3] += vv.w;
    ss[0] += vv.x * vv.x; ss[1] += vv.y * vv.y; ss[2] += vv.z * vv.z; ss[3] += vv.w * vv.w;
  }
#pragma unroll
  for (int i = 0; i < 4; ++i) { srs_[qd * 4 + i][c] = s[i]; srq_[qd * 4 + i][c] = ss[i]; }
  __syncthreads();
  if (tid < 32) {
    float t1 = 0.f, t2 = 0.f;
#pragma unroll
    for (int j = 0; j < 32; ++j) { t1 += srs_[tid][j]; t2 += srq_[tid][j]; }
    float mu = t1 * (1.f / 256.f);
    smu[tid] = mu;
    sst[tid] = rsqrtf(t2 * (1.f / 256.f) - mu * mu + 1e-5f);
  }
  __syncthreads();
  for (int tok = 0; tok < 32; ++tok) {
    float val = sx[tok][tid];
    float mu = smu[tok], rs = sst[tok];
    size_t m = (size_t)(m0 + tok) * 256 + tid;
    xtok[m] = val;
    xln[m]  = f2bf((val - mu) * rs * wreg + breg);
  }
}

// ---------------- LayerNorm (over 256) fp32 token-major src -> bf16 dst
__global__ __launch_bounds__(256)
void k_ln(const float* __restrict__ src, const float* __restrict__ w, const float* __restrict__ b,
          u16* __restrict__ dst) {
  int tid = threadIdx.x;
  int tk = tid >> 2, p = tid & 3;
  size_t m = (size_t)blockIdx.x * 64 + tk;
  const float4* row = (const float4*)(src + m * 256 + p * 64);
  float4 r[16];
  float s = 0.f, ss = 0.f;
#pragma unroll
  for (int j = 0; j < 16; ++j) {
    r[j] = row[j];
    s  += r[j].x + r[j].y + r[j].z + r[j].w;
    ss += r[j].x*r[j].x + r[j].y*r[j].y + r[j].z*r[j].z + r[j].w*r[j].w;
  }
  __shared__ float sb1[256], sb2[256];
  sb1[tid] = s; sb2[tid] = ss;
  __syncthreads();
  int base = tk << 2;
  s  = sb1[base] + sb1[base+1] + sb1[base+2] + sb1[base+3];
  ss = sb2[base] + sb2[base+1] + sb2[base+2] + sb2[base+3];
  float mu = s * (1.f / 256.f);
  float rstd = rsqrtf(ss * (1.f / 256.f) - mu * mu + 1e-5f);
  ushort4* drow = (ushort4*)(dst + m * 256 + p * 64);
#pragma unroll
  for (int j = 0; j < 16; ++j) {
    int c = p * 64 + j * 4;
    ushort4 o;
    o.x = f2bf((r[j].x - mu) * rstd * w[c]     + b[c]);
    o.y = f2bf((r[j].y - mu) * rstd * w[c + 1] + b[c + 1]);
    o.z = f2bf((r[j].z - mu) * rstd * w[c + 2] + b[c + 2]);
    o.w = f2bf((r[j].w - mu) * rstd * w[c + 3] + b[c + 3]);
    drow[j] = o;
  }
}

// ---------------- map GEMM: xln(Mc,256) x wmapT(512,256) + bias -> f bf16 (Mc,512)
__global__ __launch_bounds__(256)
void k_gemm_map(const u16* __restrict__ xln, const u16* __restrict__ wT,
                const float* __restrict__ bias, u16* __restrict__ f) {
  __shared__ __align__(16) u16 sm[16384];
  int m0 = blockIdx.x * 128, n0 = blockIdx.y * 128;
  f4v acc[4][4];
#pragma unroll
  for (int i = 0; i < 4; ++i)
#pragma unroll
    for (int j = 0; j < 4; ++j) acc[i][j] = (f4v){0.f, 0.f, 0.f, 0.f};
  gemm_core<256>(xln, wT, m0, n0, sm, acc);
  const int tid = threadIdx.x, lane = tid & 63, wave = tid >> 6;
  const int wr = wave >> 1, wc = wave & 1, q = lane >> 4, l15 = lane & 15;
#pragma unroll
  for (int ni = 0; ni < 4; ++ni) {
    int n = n0 + wc * 64 + ni * 16 + l15;
    float bz = bias[n];
#pragma unroll
    for (int mi = 0; mi < 4; ++mi) {
      int m = m0 + wr * 64 + mi * 16 + q * 4;
#pragma unroll
      for (int rr = 0; rr < 4; ++rr)
        f[(size_t)(m + rr) * 512 + n] = f2bf(acc[mi][ni][rr] + bz);
    }
  }
}

// ---------------- proj GEMM: ycat(Mc,256) x wprojT(256,256) + bias + skip (in-place xtok)
__global__ __launch_bounds__(256)
void k_gemm_proj(const u16* __restrict__ ycat, const u16* __restrict__ wT,
                 const float* __restrict__ bias, float* __restrict__ out1) {
  __shared__ __align__(16) u16 sm[16384];
  int m0 = blockIdx.x * 128, n0 = blockIdx.y * 128;
  f4v acc[4][4];
#pragma unroll
  for (int i = 0; i < 4; ++i)
#pragma unroll
    for (int j = 0; j < 4; ++j) acc[i][j] = (f4v){0.f, 0.f, 0.f, 0.f};
  gemm_core<256>(ycat, wT, m0, n0, sm, acc);
  const int tid = threadIdx.x, lane = tid & 63, wave = tid >> 6;
  const int wr = wave >> 1, wc = wave & 1, q = lane >> 4, l15 = lane & 15;
#pragma unroll
  for (int ni = 0; ni < 4; ++ni) {
    int n = n0 + wc * 64 + ni * 16 + l15;
    float bz = bias[n];
#pragma unroll
    for (int mi = 0; mi < 4; ++mi) {
      int m = m0 + wr * 64 + mi * 16 + q * 4;
#pragma unroll
      for (int rr = 0; rr < 4; ++rr) {
        size_t idx = (size_t)(m + rr) * 256 + n;
        out1[idx] = out1[idx] + acc[mi][ni][rr] + bz;
      }
    }
  }
}

// ---------------- mlp1 GEMM: xln2(Mc,256) x w1T(1024,256) + bias -> GELU -> hmid bf16 (Mc,1024)
__global__ __launch_bounds__(256)
void k_gemm_mlp1(const u16* __restrict__ xln2, const u16* __restrict__ wT,
                 const float* __restrict__ bias, u16* __restrict__ hmid) {
  __shared__ __align__(16) u16 sm[16384];
  int m0 = blockIdx.x * 128, n0 = blockIdx.y * 128;
  f4v acc[4][4];
#pragma unroll
  for (int i = 0; i < 4; ++i)
#pragma unroll
    for (int j = 0; j < 4; ++j) acc[i][j] = (f4v){0.f, 0.f, 0.f, 0.f};
  gemm_core<256>(xln2, wT, m0, n0, sm, acc);
  const int tid = threadIdx.x, lane = tid & 63, wave = tid >> 6;
  const int wr = wave >> 1, wc = wave & 1, q = lane >> 4, l15 = lane & 15;
#pragma unroll
  for (int ni = 0; ni < 4; ++ni) {
    int n = n0 + wc * 64 + ni * 16 + l15;
    float bz = bias[n];
#pragma unroll
    for (int mi = 0; mi < 4; ++mi) {
      int m = m0 + wr * 64 + mi * 16 + q * 4;
#pragma unroll
      for (int rr = 0; rr < 4; ++rr) {
        float h = acc[mi][ni][rr] + bz;
        float g = 0.5f * h * (1.f + erff(h * 0.70710678118654752f));
        hmid[(size_t)(m + rr) * 1024 + n] = f2bf(g);
      }
    }
  }
}

// ---------------- mlp2 GEMM: hmid(Mc,1024) x w2T(256,1024) + bias + out1 -> d_out (B,C,T,V)
__global__ __launch_bounds__(256)
void k_gemm_mlp2(const u16* __restrict__ hmid, const u16* __restrict__ wT,
                 const float* __restrict__ bias, const float* __restrict__ out1,
                 float* __restrict__ out, int b0) {
  __shared__ __align__(16) u16 sm[16384];   // 32KB dbuf tiles; transpose scratch overlays after K-loop
  int m0 = blockIdx.x * 128, n0 = blockIdx.y * 128;
  f4v acc[4][4];
#pragma unroll
  for (int i = 0; i < 4; ++i)
#pragma unroll
    for (int j = 0; j < 4; ++j) acc[i][j] = (f4v){0.f, 0.f, 0.f, 0.f};
  gemm_core<1024>(hmid, wT, m0, n0, sm, acc);
  const int tid = threadIdx.x, lane = tid & 63, wave = tid >> 6;
  const int wr = wave >> 1, wc = wave & 1, q = lane >> 4, l15 = lane & 15;
  float* twv = (float*)sm + wave * 16 * 65;   // 4 waves * 1040 floats = 16640 B <= 32768
  int mbase = m0 + wr * 64;
  int bglob = b0 + mbase / TVV;
  int tvb = mbase % TVV;
  for (int ni = 0; ni < 4; ++ni) {
    int n = n0 + wc * 64 + ni * 16 + l15;
    float bz = bias[n];
#pragma unroll
    for (int mi = 0; mi < 4; ++mi) {
      int ml = mi * 16 + q * 4;
#pragma unroll
      for (int rr = 0; rr < 4; ++rr) {
        int m = mbase + ml + rr;
        twv[l15 * 65 + ml + rr] = acc[mi][ni][rr] + bz + out1[(size_t)m * 256 + n];
      }
    }
    __syncthreads();
#pragma unroll
    for (int np = 0; np < 16; ++np) {
      int n2 = n0 + wc * 64 + ni * 16 + np;
      out[((size_t)bglob * 256 + n2) * TVV + tvb + lane] = twv[np * 65 + lane];
    }
    __syncthreads();
  }
}

// ---------------- grouped graph conv over V: f ch 0..63 -> ycat ch 0..63
__global__ __launch_bounds__(256)
void k_gconv(const u16* __restrict__ f, const float* __restrict__ gw,
             u16* __restrict__ ycat) {
  __shared__ float sf[50][64];
  int bc = blockIdx.x >> 6, t = blockIdx.x & 63;
  int tid = threadIdx.x;
  size_t tok0 = (size_t)bc * TVV + t * 50;
  for (int idx = tid; idx < 3200; idx += 256) {
    int u = idx >> 6, oc = idx & 63;
    sf[u][oc] = bf2f(f[(tok0 + u) * 512 + oc]);
  }
  __syncthreads();
  for (int idx = tid; idx < 3200; idx += 256) {
    int v = idx >> 6, oc = idx & 63;
    const float* gr = gw + ((size_t)(oc >> 3) * 50 + v) * 50;
    float s = 0.f;
#pragma unroll 10
    for (int u = 0; u < 50; ++u) s += sf[u][oc] * gr[u];
    ycat[(tok0 + v) * 256 + oc] = f2bf(s);
  }
}

// ---------------- grouped temporal conv k=7 pad3: f ch 64..127 -> ycat ch 64..127
__global__ __launch_bounds__(256)
void k_tconv(const u16* __restrict__ f, const float* __restrict__ tw,
             const float* __restrict__ tb, u16* __restrict__ ycat) {
  __shared__ float sw[64 * 57];
  int bc = blockIdx.x >> 6, t = blockIdx.x & 63;
  int tid = threadIdx.x;
  for (int idx = tid; idx < 64 * 56; idx += 256) {
    int oc = idx / 56, k = idx - oc * 56;
    sw[oc * 57 + k] = tw[idx];
  }
  __syncthreads();
  size_t base = (size_t)bc * TVV;
  for (int idx = tid; idx < 3200; idx += 256) {
    int v = idx >> 6, oc = idx & 63;
    int g = oc >> 3;
    float s = tb[oc];
#pragma unroll
    for (int kt = 0; kt < 7; ++kt) {
      int ts = t + kt - 3;
      if (ts < 0 || ts >= 64) continue;
      s8v fv = *(const s8v*)(f + (base + ts * 50 + v) * 512 + 64 + g * 8);
      const float* wr_ = sw + oc * 57 + kt;
#pragma unroll
      for (int ic = 0; ic < 8; ++ic) s += bf2f((u16)fv[ic]) * wr_[ic * 7];
    }
    ycat[(base + t * 50 + v) * 256 + 64 + oc] = f2bf(s);
  }
}

// ---------------- windowed hyperbolic linear attention -> ycat ch 128..255
__global__ __launch_bounds__(256)
void k_attn(const u16* __restrict__ f, u16* __restrict__ ycat) {
  int mode = blockIdx.z, bc = blockIdx.y;
  int wt = blockIdx.x / 5, wv = blockIdx.x % 5;
  __shared__ float parts[80][97];
  __shared__ float kvb[256];
  __shared__ float obuf[80][33];
  __shared__ float scl[80];
  __shared__ float pp[80][4];
  int tid = threadIdx.x;
  size_t base = (size_t)bc * TVV;
  int ch0 = 128 + mode * 96;
  for (int idx = tid; idx < 80 * 96; idx += 256) {
    int n = idx / 96, ch = idx - n * 96;
    int lt = n / 10, lv = n - lt * 10;
    int t = (mode < 2) ? (wt * 8 + lt) : (lt * 8 + wt);
    int v = ((mode & 1) == 0) ? (wv * 10 + lv) : (lv * 5 + wv);
    parts[n][ch] = bf2f(f[(base + t * 50 + v) * 512 + ch0 + ch]);
  }
  __syncthreads();
  // euc->poincare norm: parallel partial sums (80 rows x 4 partials of 24 ch)
  for (int idx = tid; idx < 320; idx += 256) {
    int n = idx >> 2, p = idx & 3;
    const float* pr = &parts[n][p * 24];
    float s = 0.f;
#pragma unroll
    for (int ch = 0; ch < 24; ++ch) { float val = pr[ch]; s += val * val; }
    pp[n][p] = s;
  }
  __syncthreads();
  if (tid < 80) {
    float s = pp[tid][0] + pp[tid][1] + pp[tid][2] + pp[tid][3];
    float nrm = fmaxf(sqrtf(s), 1e-10f);
    scl[tid] = tanhf(nrm) / nrm;
  }
  __syncthreads();
  for (int idx = tid; idx < 80 * 96; idx += 256) {
    int n = idx / 96, ch = idx - n * 96;
    parts[n][ch] *= scl[n];
  }
  __syncthreads();
  {
    int h = tid >> 6, dd = (tid >> 3) & 7, e = tid & 7;
    float s = 0.f;
    for (int n = 0; n < 80; ++n)
      s += parts[n][32 + h * 8 + dd] * parts[n][64 + h * 8 + e];
    kvb[tid] = s;
  }
  __syncthreads();
  if (tid < 32) {
    int h = tid >> 3, dd = tid & 7;
    float* r = &kvb[h * 64 + dd * 8];
    float mx = r[0];
    for (int e = 1; e < 8; ++e) mx = fmaxf(mx, r[e]);
    float ex[8]; float sm2 = 0.f;
    for (int e = 0; e < 8; ++e) { ex[e] = expf(r[e] - mx); sm2 += ex[e]; }
    float inv = 1.f / sm2;
    for (int e = 0; e < 8; ++e) r[e] = ex[e] * inv;
  }
  __syncthreads();
  for (int idx = tid; idx < 80 * 32; idx += 256) {
    int n = idx >> 5, cc = idx & 31;
    int h = cc >> 3, m_ = cc & 7;
    float s = 0.f;
#pragma unroll
    for (int i = 0; i < 8; ++i)
      s += parts[n][h * 8 + i] * kvb[h * 64 + m_ * 8 + i];
    obuf[n][cc] = s * 0.5f;
  }
  __syncthreads();
  // poincare->euc norm: parallel partial sums (80 rows x 2 partials of 16 ch)
  for (int idx = tid; idx < 160; idx += 256) {
    int n = idx >> 1, p = idx & 1;
    const float* orow = &obuf[n][p * 16];
    float s = 0.f;
#pragma unroll
    for (int cc = 0; cc < 16; ++cc) { float val = orow[cc]; s += val * val; }
    pp[n][p] = s;
  }
  __syncthreads();
  if (tid < 80) {
    float nn = sqrtf(pp[tid][0] + pp[tid][1]);
    nn = fminf(fmaxf(nn, 1e-10f), 1.f - 1e-5f);
    scl[tid] = -atanhf(nn) / nn;
  }
  __syncthreads();
  for (int idx = tid; idx < 80 * 32; idx += 256) {
    int n = idx >> 5, cc = idx & 31;
    int lt = n / 10, lv = n - lt * 10;
    int t = (mode < 2) ? (wt * 8 + lt) : (lt * 8 + wt);
    int v = ((mode & 1) == 0) ? (wv * 10 + lv) : (lv * 5 + wv);
    ycat[(base + t * 50 + v) * 256 + 128 + mode * 32 + cc] = f2bf(obuf[n][cc] * scl[n]);
  }
}

extern "C" void kernel_launch(void* const* d_in, const int* in_sizes, int n_in,
                              void* d_out, int out_size, void* d_ws, size_t ws_size,
                              hipStream_t stream) {
  const float* x       = (const float*)d_in[0];
  const float* n1w     = (const float*)d_in[1];
  const float* n1b     = (const float*)d_in[2];
  const float* map_w   = (const float*)d_in[3];
  const float* map_b   = (const float*)d_in[4];
  const float* gconv   = (const float*)d_in[5];
  const float* tconv_w = (const float*)d_in[6];
  const float* tconv_b = (const float*)d_in[7];
  const float* proj_w  = (const float*)d_in[8];
  const float* proj_b  = (const float*)d_in[9];
  const float* n2w     = (const float*)d_in[10];
  const float* n2b     = (const float*)d_in[11];
  const float* w1      = (const float*)d_in[12];
  const float* b1      = (const float*)d_in[13];
  const float* w2      = (const float*)d_in[14];
  const float* b2      = (const float*)d_in[15];
  float* out = (float*)d_out;

  // per-token ws: xtok/out1 fp32 (1024 B) | region2 2048 B: f bf16 (Mc,512) overlaid
  // with hmid bf16 (Mc,1024) | xln bf16 (512 B) | ycat bf16 (512 B) = 4096 B/token
  const size_t WB = (size_t)(512 * 256 + 256 * 256 + 1024 * 256 + 256 * 1024) * 2;
  int CH = 32;
  while (CH > 1 && (size_t)CH * TVV * 4096 + WB > ws_size) CH >>= 1;
  if ((size_t)CH * TVV * 4096 + WB > ws_size) return;
  const int Mc = CH * TVV;
  const int nch = BB / CH;

  char* ws = (char*)d_ws;
  float* xtok   = (float*)ws;                                // (Mc,256) fp32; becomes out1
  u16* f        = (u16*)(ws + (size_t)Mc * 1024);            // (Mc,512) bf16
  u16* hmid     = f;                                         // (Mc,1024) bf16 overlay
  u16* xln      = (u16*)(ws + (size_t)Mc * 3072);            // (Mc,256) bf16
  u16* ycat     = (u16*)(ws + (size_t)Mc * 3584);            // (Mc,256) bf16
  u16* wmapT    = (u16*)(ws + (size_t)Mc * 4096);            // (512,256)
  u16* wprojT   = wmapT + 512 * 256;                         // (256,256)
  u16* w1T      = wprojT + 256 * 256;                        // (1024,256)
  u16* w2T      = w1T + 1024 * 256;                          // (256,1024)

  k_wprep<<<dim3(512), 256, 0, stream>>>(map_w, wmapT, 256, 512);
  k_wprep<<<dim3(256), 256, 0, stream>>>(proj_w, wprojT, 256, 256);
  k_wprep<<<dim3(1024), 256, 0, stream>>>(w1, w1T, 256, 1024);
  k_wprep<<<dim3(1024), 256, 0, stream>>>(w2, w2T, 1024, 256);

  for (int c = 0; c < nch; ++c) {
    int b0 = c * CH;
    k_lnx<<<dim3(Mc / 32), 256, 0, stream>>>(x, b0, n1w, n1b, xtok, xln);
    k_gemm_map<<<dim3(Mc / 128, 4), 256, 0, stream>>>(xln, wmapT, map_b, f);
    k_gconv<<<dim3(CH * 64), 256, 0, stream>>>(f, gconv, ycat);
    k_tconv<<<dim3(CH * 64), 256, 0, stream>>>(f, tconv_w, tconv_b, ycat);
    k_attn<<<dim3(40, CH, 4), 256, 0, stream>>>(f, ycat);
    k_gemm_proj<<<dim3(Mc / 128, 2), 256, 0, stream>>>(ycat, wprojT, proj_b, xtok);
    k_ln<<<dim3(Mc / 64), 256, 0, stream>>>(xtok, n2w, n2b, xln);
    k_gemm_mlp1<<<dim3(Mc / 128, 8), 256, 0, stream>>>(xln, w1T, b1, hmid);
    k_gemm_mlp2<<<dim3(Mc / 128, 2), 256, 0, stream>>>(hmid, w2T, b2, xtok, out, b0);
  }
}